// Round 8
// baseline (1849.417 us; speedup 1.0000x reference)
//
#include <hip/hip_runtime.h>
#include <hip/hip_bf16.h>
#include <cstddef>

#define THRESH 1e-6f
#define NBLK 256        // scan grid: 1 block/CU, 8 waves = 2 waves/SIMD
#define NTHR 512
#define SPIN_LIMIT (1 << 20)

__device__ __forceinline__ float thrf(float x) { return x > THRESH ? x : 0.0f; }
__device__ __forceinline__ float sigm(float x) { return 1.0f / (1.0f + expf(-x)); }
__device__ __forceinline__ float dot4(float4 a, float4 b) {
    return a.x * b.x + a.y * b.y + a.z * b.z + a.w * b.w;
}

// ---------------------------------------------------------------------------
// Tiled fp32 GEMM, BM=32 BN=64 BK=32, 256 threads, 2x4 micro-tile.
// 2 blocks/CU -> 2 waves/SIMD (R7's 64x64 embed ran 1 wave/SIMD, latency-bound).
// GATHER: A row r = thr(W1[tok[bm+r]][k] + b1[k])   (embed path)
// BT:     B is (N,K) row-major, use B^T                (xproj path)
// ---------------------------------------------------------------------------
template <bool BT, bool GATHER, bool DO_THR>
__global__ __launch_bounds__(256) void k_gemm(const float* __restrict__ A,
                                              const float* __restrict__ Bm,
                                              const float* __restrict__ bias,
                                              float* __restrict__ C,
                                              const int* __restrict__ tok,
                                              const float* __restrict__ b1,
                                              const float* __restrict__ W1,
                                              int M, int N, int K) {
    constexpr int BM = 32, BN = 64, BK = 32;
    __shared__ float As[BK][BM + 1];
    __shared__ float Bs[BK][BN];

    const int tid = threadIdx.x;
    const int bm = blockIdx.x * BM;
    const int bn = blockIdx.y * BN;
    const int tn = (tid & 15) * 4;
    const int tm = (tid >> 4) * 2;

    float acc[2][4] = {};

    for (int k0 = 0; k0 < K; k0 += BK) {
        // ---- A tile (BM x BK) -> As[k][m]; 1 f4 per thread ----
        {
            int c4 = (tid & 7) * 4;
            int r  = tid >> 3;       // 0..31
            float4 v;
            if (GATHER) {
                int tv = tok[bm + r];
                float4 w  = *(const float4*)(W1 + (size_t)tv * K + k0 + c4);
                float4 bb = *(const float4*)(b1 + k0 + c4);
                v.x = thrf(w.x + bb.x); v.y = thrf(w.y + bb.y);
                v.z = thrf(w.z + bb.z); v.w = thrf(w.w + bb.w);
            } else {
                v = *(const float4*)(A + (size_t)(bm + r) * K + k0 + c4);
            }
            As[c4 + 0][r] = v.x;
            As[c4 + 1][r] = v.y;
            As[c4 + 2][r] = v.z;
            As[c4 + 3][r] = v.w;
        }
        // ---- B tile (BK x BN); 2 per thread ----
        if (!BT) {
            for (int i = tid; i < BK * BN / 4; i += 256) {
                int n4 = (i & 15) * 4;
                int kk = i >> 4;
                *(float4*)&Bs[kk][n4] = *(const float4*)(Bm + (size_t)(k0 + kk) * N + bn + n4);
            }
        } else {
            for (int i = tid; i < BN * BK / 4; i += 256) {
                int c4 = (i & 7) * 4;
                int n  = i >> 3;     // 0..63
                float4 v = *(const float4*)(Bm + (size_t)(bn + n) * K + k0 + c4);
                Bs[c4 + 0][n] = v.x;
                Bs[c4 + 1][n] = v.y;
                Bs[c4 + 2][n] = v.z;
                Bs[c4 + 3][n] = v.w;
            }
        }
        __syncthreads();

        for (int k = 0; k < BK; ++k) {
            float a0 = As[k][tm + 0], a1 = As[k][tm + 1];
            float b0 = Bs[k][tn + 0], b1v = Bs[k][tn + 1];
            float b2v = Bs[k][tn + 2], b3v = Bs[k][tn + 3];
            acc[0][0] += a0 * b0;  acc[0][1] += a0 * b1v;
            acc[0][2] += a0 * b2v; acc[0][3] += a0 * b3v;
            acc[1][0] += a1 * b0;  acc[1][1] += a1 * b1v;
            acc[1][2] += a1 * b2v; acc[1][3] += a1 * b3v;
        }
        __syncthreads();
    }

    const float4 bv = *(const float4*)(bias + bn + tn);
    for (int i = 0; i < 2; ++i) {
        int m = bm + tm + i;
        float4 o;
        o.x = acc[i][0] + bv.x;
        o.y = acc[i][1] + bv.y;
        o.z = acc[i][2] + bv.z;
        o.w = acc[i][3] + bv.w;
        if (DO_THR) { o.x = thrf(o.x); o.y = thrf(o.y); o.z = thrf(o.z); o.w = thrf(o.w); }
        *(float4*)(C + (size_t)m * N + bn + tn) = o;
    }
}

// ---------------------------------------------------------------------------
// K2: persistent GRU scan (h-part only; x-projection precomputed into xp).
// 256 blocks x 512 threads.  Block bid owns j in {bid*2, bid*2+1} x 3 gates
// = 6 W_hh rows in LDS.  Thread (b = tid&31, ks = tid>>5 in [0,16)):
// 6 rows x K-chunk 32, each h dword read once per block.
//
// Distributed flag barrier (vs R7's centralized block0+gen = 2 extra LLC
// hops): every block's wave 0 polls all 256 flags RELAXED; one acquire
// fence per block per step.  Arrival flag posted IMMEDIATELY after the
// h-store drain (nothing else on that path).
// ---------------------------------------------------------------------------
__global__ __launch_bounds__(NTHR) void k_gru_scan(const float* __restrict__ xp,   // (128,32,1536), b_ih included
                                                   const float* __restrict__ W_hh, // (1536,512)
                                                   const float* __restrict__ b_hh,
                                                   float* __restrict__ h0,         // zeroed; final h
                                                   float* __restrict__ h1,
                                                   unsigned* __restrict__ flags) { // NBLK lines, stride 32 u32
    __shared__ __align__(16) float Whl[6][516];   // 12384 B
    __shared__ __align__(16) float red[16][200];  // 12800 B ; stride 200 -> 2-way alias (free)
    __shared__ float bsh[6];

    const int tid = threadIdx.x;
    const int bid = blockIdx.x;
    const int b  = tid & 31;
    const int ks = tid >> 5;        // 0..15
    const int kb = ks * 32;

    // ---- stage 6 W_hh rows + biases (once); row r = g*2 + jl ----
    for (int idx = tid; idx < 6 * 128; idx += NTHR) {
        int r = idx >> 7, k4 = (idx & 127) << 2;
        int row = (r >> 1) * 512 + bid * 2 + (r & 1);
        *(float4*)&Whl[r][k4] = *(const float4*)(W_hh + (size_t)row * 512 + k4);
    }
    if (tid < 6) bsh[tid] = b_hh[(tid >> 1) * 512 + bid * 2 + (tid & 1)];
    __syncthreads();

    for (int t = 0; t < 128; ++t) {
        if (t) {
            if (tid < 64) {
                int spins = 0;
                bool ok;
                do {
                    ok = true;
#pragma unroll
                    for (int i = 0; i < 4; ++i) {
                        unsigned f = __hip_atomic_load(&flags[(tid * 4 + i) * 32],
                                                       __ATOMIC_RELAXED, __HIP_MEMORY_SCOPE_AGENT);
                        ok &= (f >= (unsigned)t);
                    }
                    if (ok) break;
                    __builtin_amdgcn_s_sleep(1);
                } while (++spins < SPIN_LIMIT);
                if (tid == 0) __builtin_amdgcn_fence(__ATOMIC_ACQUIRE, "agent");  // one inv/step
            }
            __syncthreads();
        }
        const float* hc = (t & 1) ? h1 : h0;   // t=0 reads zeroed h0
        float*       hn = (t & 1) ? h0 : h1;

        // early loads for the finalize threads: h_prev + xp gates (latency
        // hidden under the h-part compute below)
        float hp = 0.f, xr = 0.f, xz = 0.f, xn = 0.f;
        if (tid < 64) {
            int jl = tid >> 5, bb = tid & 31;
            int j = bid * 2 + jl;
            hp = hc[(size_t)bb * 512 + j];
            const float* xpt = xp + ((size_t)t * 32 + bb) * 1536;
            xr = xpt[j];
            xz = xpt[512 + j];
            xn = xpt[1024 + j];
        }

        // ---- h-part: 6 rows x K-chunk 32, h slice read once ----
        float acc[6] = {};
        {
            const float* hb = hc + (size_t)b * 512 + kb;
            float4 hv[8];
#pragma unroll
            for (int i = 0; i < 8; ++i) hv[i] = *(const float4*)(hb + i * 4);
#pragma unroll
            for (int i = 0; i < 8; ++i) {
#pragma unroll
                for (int r = 0; r < 6; ++r) {
                    float4 w = *(const float4*)&Whl[r][kb + i * 4];
                    acc[r] += dot4(hv[i], w);
                }
            }
        }
#pragma unroll
        for (int r = 0; r < 6; ++r) red[ks][r * 32 + b] = acc[r];
        __syncthreads();

        // ---- reduce 16 k-partials: 192 threads, one column each ----
        if (tid < 192) {
            float s = 0.f;
#pragma unroll
            for (int q = 0; q < 16; ++q) s += red[q][tid];
            red[0][tid] = s;
        }
        __syncthreads();

        // ---- gates: 64 threads (jl = tid>>5, b = tid&31) ----
        if (tid < 64) {
            int jl = tid >> 5, bb = tid & 31;
            float sh0 = red[0][(0 + jl) * 32 + bb];
            float sh1 = red[0][(2 + jl) * 32 + bb];
            float sh2 = red[0][(4 + jl) * 32 + bb];
            float r = sigm(xr + sh0 + bsh[jl]);          // xp includes b_ih
            float z = sigm(xz + sh1 + bsh[2 + jl]);
            float n = tanhf(xn + r * (sh2 + bsh[4 + jl]));
            hn[(size_t)bb * 512 + bid * 2 + jl] = (1.0f - z) * n + z * hp;
        }
        __syncthreads();   // compiler drains vmcnt before s_barrier -> h stores complete
        if (tid == 0) {
            __builtin_amdgcn_fence(__ATOMIC_RELEASE, "agent");  // wb L2: h visible at LLC
            __hip_atomic_store(&flags[bid * 32], (unsigned)(t + 1),
                               __ATOMIC_RELAXED, __HIP_MEMORY_SCOPE_AGENT);
        }
    }
    // final h in h0 (t=127 wrote hn = h0)
}

// ---------------------------------------------------------------------------
// K3: head.  out[b][o] = sum_k h[b][k] * W3[k][o] + b3[o]
// ---------------------------------------------------------------------------
__global__ __launch_bounds__(256) void k_head(const float* __restrict__ h,
                                              const float* __restrict__ W3,
                                              const float* __restrict__ b3,
                                              float* __restrict__ out) {
    const int b = blockIdx.x;
    const int o = threadIdx.x;
    const float* hrow = h + (size_t)b * 512;
    float acc = b3[o];
#pragma unroll 8
    for (int k = 0; k < 512; ++k)
        acc += hrow[k] * W3[(size_t)k * 256 + o];
    out[(size_t)b * 256 + o] = acc;
}

// ---------------------------------------------------------------------------
extern "C" void kernel_launch(void* const* d_in, const int* in_sizes, int n_in,
                              void* d_out, int out_size, void* d_ws, size_t ws_size,
                              hipStream_t stream) {
    // setup_inputs() dict order:
    //   0:input 1:W1 2:b1 3:W2 4:b2 5:W_ih 6:W_hh 7:b_ih 8:b_hh 9:W3 10:b3
    const int*   tok  = (const int*)d_in[0];
    const float* W1   = (const float*)d_in[1];
    const float* b1   = (const float*)d_in[2];
    const float* W2   = (const float*)d_in[3];
    const float* b2   = (const float*)d_in[4];
    const float* W_ih = (const float*)d_in[5];
    const float* W_hh = (const float*)d_in[6];
    const float* b_ih = (const float*)d_in[7];
    const float* b_hh = (const float*)d_in[8];
    const float* W3   = (const float*)d_in[9];
    const float* b3   = (const float*)d_in[10];
    float* out = (float*)d_out;

    // workspace (floats): emb 4MB | xp 24MB | h_a 64KB | flags 32KB | h_b 64KB
    float* ws  = (float*)d_ws;
    float*    emb   = ws;                       // 4096*256
    float*    xp    = ws + 1048576;             // 4096*1536
    float*    h_a   = xp + 6291456;             // 32*512
    unsigned* flags = (unsigned*)(h_a + 16384); // 256*32 u32
    float*    h_b   = (float*)(flags + 8192);   // 32*512
    // total ~28.4 MB

    // zero h_a + flags (contiguous 96KB); h_b fully written at t=0
    (void)hipMemsetAsync(h_a, 0, 16384 * sizeof(float) + 8192 * sizeof(unsigned), stream);

    // K1a: emb = thr(thr(W1[tok]+b1) @ W2 + b2)      (gather fused into A)
    k_gemm<false, true, true><<<dim3(4096 / 32, 256 / 64), 256, 0, stream>>>(
        nullptr, W2, b2, emb, tok, b1, W1, 4096, 256, 512);

    // K1b: xp = emb @ W_ih^T + b_ih                  (4096 x 1536)
    k_gemm<true, false, false><<<dim3(4096 / 32, 1536 / 64), 256, 0, stream>>>(
        emb, W_ih, b_ih, xp, nullptr, nullptr, nullptr, 4096, 1536, 256);

    // K2: persistent scan, distributed flag barrier
    k_gru_scan<<<NBLK, NTHR, 0, stream>>>(xp, W_hh, b_hh, h_a, h_b, flags);

    // K3: head on final hidden state (in h_a)
    k_head<<<32, 256, 0, stream>>>(h_a, W3, b3, out);
}